// Round 6
// baseline (96.413 us; speedup 1.0000x reference)
//
#include <hip/hip_runtime.h>

typedef short s8v __attribute__((ext_vector_type(8)));    // 8 bf16 (raw bits) = 4 VGPRs
typedef float f4v __attribute__((ext_vector_type(4)));    // MFMA accumulator

#define GAS __attribute__((address_space(1)))
#define LAS __attribute__((address_space(3)))

constexpr int KDIM = 128;
constexpr float INV_COS = 1.0f / 128.0f;
constexpr float LOG2E   = 1.4426950408889634f;
constexpr float EXP_C1  = LOG2E / 128.0f;   // exp(1 + g/128) = exp2(g*C1 + C2)
constexpr float EXP_C2  = LOG2E;

// ---- fp32 -> bf16 (RNE) ----
__device__ inline unsigned short f2bf(float f) {
    unsigned u = __float_as_uint(f);
    u += 0x7fffu + ((u >> 16) & 1u);
    return (unsigned short)(u >> 16);
}

__global__ __launch_bounds__(256) void k_convert(const float* __restrict__ X,
                                                 unsigned short* __restrict__ Xb,
                                                 unsigned* __restrict__ counter) {
    if (blockIdx.x == 0 && threadIdx.x == 0) *counter = 0;   // for k_finalize
    int idx = (blockIdx.x * 256 + threadIdx.x) * 4;
    float4 v = *(const float4*)(X + idx);
    ushort4 o;
    o.x = f2bf(v.x); o.y = f2bf(v.y); o.z = f2bf(v.z); o.w = f2bf(v.w);
    *(ushort4*)(Xb + idx) = o;
}

// ---- symmetric 128x128-tile gemm + exp + row/col sums, K split in two 64-halves ----
// LDS 32 KiB -> 5 blocks/CU (20 waves/CU) vs 2 at 64 KiB. Same staging bytes/AI.
// partial[row][128] slot map (R3/R5-verified): row r in tile-row b gets row-sum
// slots [2b,128), col-sum slots [0,2b). Exact cover, no atomics, no zero-init.
__global__ __launch_bounds__(256) void k_gemm_rowsum(const unsigned short* __restrict__ Xb,
                                                     float* __restrict__ partial) {
    __shared__ unsigned short ldsA[128 * 64];   // 16 KiB: 128 rows x 8 chunks(16B)
    __shared__ unsigned short ldsB[128 * 64];   // 16 KiB

    // linear block id -> upper-triangular (by, bx), 64x64 tile grid
    int rem = blockIdx.x;
    int by = 0;
    while (rem >= 64 - by) { rem -= 64 - by; ++by; }
    const int bx = by + rem;
    const bool offdiag = (bx != by);

    const int tid  = threadIdx.x;
    const int wave = tid >> 6;
    const int lane = tid & 63;
    const int rA = by * 128;
    const int rB = bx * 128;

    const int q    = lane >> 4;    // quad 0..3
    const int mrow = lane & 15;
    const int wm   = wave >> 1;    // 2x2 wave grid over 128x128 tile
    const int wn   = wave & 1;

    f4v acc[4][4];
#pragma unroll
    for (int a = 0; a < 4; ++a)
#pragma unroll
        for (int b = 0; b < 4; ++b)
            acc[a][b] = (f4v){0.f, 0.f, 0.f, 0.f};

    const int lr8 = lane >> 3;     // row within 8-row staging group
    const int cph = lane & 7;      // physical chunk slot (8 chunks of 16B per row)

#pragma unroll
    for (int h = 0; h < 2; ++h) {                  // K-half: cols [h*64, h*64+64)
        // ---- staging: slot (r, cph) holds global chunk cph^(r&7) of this half ----
#pragma unroll
        for (int t = 0; t < 4; ++t) {
            int g = wave * 4 + t;                  // 16 groups of 8 rows
            int r_loc = g * 8 + lr8;
            int c_log = cph ^ (r_loc & 7);
            const unsigned short* ga = Xb + (size_t)(rA + r_loc) * KDIM + (h * 8 + c_log) * 8;
            const unsigned short* gb = Xb + (size_t)(rB + r_loc) * KDIM + (h * 8 + c_log) * 8;
            __builtin_amdgcn_global_load_lds((const GAS void*)ga, (LAS void*)&ldsA[g * 512], 16, 0, 0);
            __builtin_amdgcn_global_load_lds((const GAS void*)gb, (LAS void*)&ldsB[g * 512], 16, 0, 0);
        }
        __syncthreads();

#pragma unroll
        for (int ks = 0; ks < 2; ++ks) {           // K-steps of 32 within half
            s8v af[4], bfr[4];
            int cp = (ks * 4 + q) ^ (mrow & 7);
#pragma unroll
            for (int mi = 0; mi < 4; ++mi) {
                int ra = wm * 64 + mi * 16 + mrow;
                int rb = wn * 64 + mi * 16 + mrow;
                af[mi]  = *(const s8v*)&ldsA[(ra * 8 + cp) * 8];
                bfr[mi] = *(const s8v*)&ldsB[(rb * 8 + cp) * 8];
            }
#pragma unroll
            for (int mi = 0; mi < 4; ++mi)
#pragma unroll
                for (int ni = 0; ni < 4; ++ni)
                    acc[mi][ni] = __builtin_amdgcn_mfma_f32_16x16x32_bf16(af[mi], bfr[ni], acc[mi][ni], 0, 0, 0);
        }
        if (h == 0) __syncthreads();               // LDS reuse for half 1
    }

    // ---- epilogue: e = exp2(g*C1 + C2) = exp(1 + g/128); lane holds
    // G[wm*64+mi*16+q*4+t][wn*64+ni*16+mrow]
    float rsum[4][4];
    float csum[4] = {0.f, 0.f, 0.f, 0.f};
#pragma unroll
    for (int mi = 0; mi < 4; ++mi)
#pragma unroll
        for (int t = 0; t < 4; ++t)
            rsum[mi][t] = 0.f;

#pragma unroll
    for (int mi = 0; mi < 4; ++mi)
#pragma unroll
        for (int ni = 0; ni < 4; ++ni)
#pragma unroll
            for (int t = 0; t < 4; ++t) {
                float e = exp2f(fmaf(acc[mi][ni][t], EXP_C1, EXP_C2));
                rsum[mi][t] += e;
                csum[ni]    += e;
            }

    // row-sums: reduce across mrow (16 cols) via xor 1,2,4,8
#pragma unroll
    for (int mi = 0; mi < 4; ++mi)
#pragma unroll
        for (int t = 0; t < 4; ++t) {
            float v = rsum[mi][t];
            v += __shfl_xor(v, 1);
            v += __shfl_xor(v, 2);
            v += __shfl_xor(v, 4);
            v += __shfl_xor(v, 8);
            rsum[mi][t] = v;
        }

    // lane c (=mrow) writes row (mi=c>>2, t=c&3) of its quad
    {
        const int c = mrow;
        float outv = 0.f;
#pragma unroll
        for (int mi = 0; mi < 4; ++mi)
#pragma unroll
            for (int t = 0; t < 4; ++t)
                if ((mi * 4 + t) == c) outv = rsum[mi][t];
        int row_loc = wm * 64 + (c >> 2) * 16 + q * 4 + (c & 3);
        partial[(size_t)(rA + row_loc) * 128 + (bx * 2 + wn)] = outv;
    }

    if (offdiag) {
        // col-sums: reduce across q (4 row-groups) via xor 16,32
#pragma unroll
        for (int ni = 0; ni < 4; ++ni) {
            float v = csum[ni];
            v += __shfl_xor(v, 16);
            v += __shfl_xor(v, 32);
            csum[ni] = v;
        }
        if (q == 0) {
#pragma unroll
            for (int ni = 0; ni < 4; ++ni) {
                int col_loc = wn * 64 + ni * 16 + mrow;
                partial[(size_t)(rB + col_loc) * 128 + (by * 2 + wm)] = csum[ni];
            }
        }
    }
}

// ---- finalize: 256 blocks, 4 pairs/wave; deterministic blocksum; last block reduces ----
__global__ __launch_bounds__(256) void k_finalize(const float* __restrict__ X,
                                                  const float* __restrict__ partial,
                                                  float* __restrict__ blocksum,
                                                  unsigned* __restrict__ counter,
                                                  float* __restrict__ out) {
    __shared__ float ls[4];
    __shared__ bool last;
    const int tid = threadIdx.x;
    const int wave = tid >> 6, lane = tid & 63;

    float jacc = 0.f;                              // lane 0 accumulates J^2
#pragma unroll
    for (int it = 0; it < 4; ++it) {
        int p = blockIdx.x * 16 + wave * 4 + it;   // 4096 pairs
        int i = 2 * p, j = i + 1;

        const float* pri = partial + (size_t)i * 128;
        const float* prj = partial + (size_t)j * 128;
        float pi = pri[lane] + pri[lane + 64];
        float pj = prj[lane] + prj[lane + 64];
        float xi0 = X[(size_t)i * 128 + lane], xi1 = X[(size_t)i * 128 + 64 + lane];
        float xj0 = X[(size_t)j * 128 + lane], xj1 = X[(size_t)j * 128 + 64 + lane];
        float dii = xi0 * xi0 + xi1 * xi1;
        float dij = xi0 * xj0 + xi1 * xj1;
        float djj = xj0 * xj0 + xj1 * xj1;

#pragma unroll
        for (int m = 1; m < 64; m <<= 1) {
            pi  += __shfl_xor(pi, m);
            pj  += __shfl_xor(pj, m);
            dii += __shfl_xor(dii, m);
            dij += __shfl_xor(dij, m);
            djj += __shfl_xor(djj, m);
        }
        if (lane == 0) {
            dii *= INV_COS; dij *= INV_COS; djj *= INV_COS;
            float eii = __expf(1.0f + dii);
            float eij = __expf(1.0f + dij);
            float ejj = __expf(1.0f + djj);
            float dissim = (pi - eii - eij) + (pj - eij - ejj);
            float J = __logf(1e-8f + dissim) - dij;
            jacc += (J > 0.f) ? J * J : 0.f;
        }
    }
    if (lane == 0) ls[wave] = jacc;
    __syncthreads();
    if (tid == 0) {
        blocksum[blockIdx.x] = ls[0] + ls[1] + ls[2] + ls[3];
        __threadfence();                           // release blocksum
        last = (atomicAdd(counter, 1u) == 255u);
    }
    __syncthreads();
    if (last) {
        __threadfence();                           // acquire all blocksums
        float s = blocksum[tid];
#pragma unroll
        for (int m = 1; m < 64; m <<= 1) s += __shfl_xor(s, m);
        if ((tid & 63) == 0) ls[tid >> 6] = s;
        __syncthreads();
        if (tid == 0) out[0] = (ls[0] + ls[1] + ls[2] + ls[3]) * (1.0f / 16384.0f);
    }
}

extern "C" void kernel_launch(void* const* d_in, const int* in_sizes, int n_in,
                              void* d_out, int out_size, void* d_ws, size_t ws_size,
                              hipStream_t stream) {
    const float* X = (const float*)d_in[0];
    char* ws = (char*)d_ws;
    unsigned short* Xb = (unsigned short*)ws;             // 2 MiB bf16 input
    float* partial    = (float*)(ws + (2u << 20));        // 4 MiB: partial[8192][128]
    float* blocksum   = (float*)(ws + (6u << 20));        // 1 KiB
    unsigned* counter = (unsigned*)(ws + (7u << 20));     // 4 B
    float* out        = (float*)d_out;

    hipLaunchKernelGGL(k_convert,     dim3(1024), dim3(256), 0, stream, X, Xb, counter);
    hipLaunchKernelGGL(k_gemm_rowsum, dim3(2080), dim3(256), 0, stream, Xb, partial);
    hipLaunchKernelGGL(k_finalize,    dim3(256),  dim3(256), 0, stream, X, partial, blocksum, counter, out);
}